// Round 1
// baseline (93.560 us; speedup 1.0000x reference)
//
#include <hip/hip_runtime.h>
#include <hip/hip_bf16.h>
#include <math.h>

#define NROW 4096
#define DIM  512
#define M2   8192                     // 2N rows
#define SELF_EXP 7.3890560989306495f  // exp(1/T) = exp(2)
#define TGRID 32                      // M2 / 256 tile grid
#define NOFF  (TGRID * (TGRID - 1) / 2)   // 496 strictly-upper tiles
#define NBLK  (NOFF + TGRID)              // 528 total (32 diagonal last)
#define BK    64                      // K-step (elements)
#define NKT   (DIM / BK)              // 8 K-tiles
#define LDS_BUF   65536               // bytes per double-buffer half
#define LDS_TOTAL 131072

typedef __hip_bfloat16 bf16;
typedef __attribute__((ext_vector_type(8))) short short8;   // 8 bf16 (4 VGPRs)
typedef __attribute__((ext_vector_type(4))) float f32x4;

// ---------------------------------------------------------------------------
// Kernel 1: fused row-normalize (x,y -> bf16 ns[8192][512]) + positive-pair
// cosine partial + rowsum zeroing. (unchanged)
// ---------------------------------------------------------------------------
__global__ __launch_bounds__(256) void norm_pos_kernel(
    const float* __restrict__ x, const float* __restrict__ y,
    bf16* __restrict__ ns, float* __restrict__ pospart,
    float* __restrict__ rowsum)
{
    const int i = blockIdx.x;
    const int t = threadIdx.x;
    const float2 a = ((const float2*)(x + (size_t)i * DIM))[t];
    const float2 b = ((const float2*)(y + (size_t)i * DIM))[t];
    float sx = a.x * a.x + a.y * a.y;
    float sy = b.x * b.x + b.y * b.y;
    float dt = a.x * b.x + a.y * b.y;
    #pragma unroll
    for (int o = 1; o < 64; o <<= 1) {
        sx += __shfl_xor(sx, o);
        sy += __shfl_xor(sy, o);
        dt += __shfl_xor(dt, o);
    }
    __shared__ float rd[12];
    const int wid = t >> 6, lane = t & 63;
    if (lane == 0) { rd[wid] = sx; rd[4 + wid] = sy; rd[8 + wid] = dt; }
    __syncthreads();
    const float SX = rd[0] + rd[1] + rd[2] + rd[3];
    const float SY = rd[4] + rd[5] + rd[6] + rd[7];
    const float D  = rd[8] + rd[9] + rd[10] + rd[11];
    const float rnx = rsqrtf(SX), rny = rsqrtf(SY);

    bf16 a0 = __float2bfloat16(a.x * rnx), a1 = __float2bfloat16(a.y * rnx);
    bf16 b0 = __float2bfloat16(b.x * rny), b1 = __float2bfloat16(b.y * rny);
    ushort2 sa, sb;
    sa.x = *(unsigned short*)&a0; sa.y = *(unsigned short*)&a1;
    sb.x = *(unsigned short*)&b0; sb.y = *(unsigned short*)&b1;
    ((ushort2*)(void*)(ns + (size_t)i * DIM))[t] = sa;
    ((ushort2*)(void*)(ns + (size_t)(i + NROW) * DIM))[t] = sb;

    if (t == 0) pospart[i] = D * rnx * rny;
    if (t < 2)  rowsum[2 * i + t] = 0.f;
}

// ---------------------------------------------------------------------------
// Kernel 2: symmetric Gram, 256x256 tiles, 8-wave 4-phase/K-tile schedule
// (ported from the verified 256^2 8-phase template): BK=64, 128 KiB dbuf LDS,
// T2 XOR-swizzle (row&7)<<4 (linear gload_lds dest + inverse-swizzled global
// source), staging 2-3 phases ahead of its single per-K-tile vmcnt drain,
// setprio(1) around MFMA clusters. Upper-triangle tiles first (XCD-chunked),
// 32 diagonal tiles last; diagonal tiles skip the strictly-lower-quadrant
// waves and recover those rowsums from upper-quadrant colsums by symmetry.
// ---------------------------------------------------------------------------
__device__ __forceinline__ void glds16(const char* g, char* l)
{
    __builtin_amdgcn_global_load_lds(
        (const __attribute__((address_space(1))) void*)g,
        (__attribute__((address_space(3))) void*)l, 16, 0, 0);
}

// Stage one full 32 KiB matrix panel (256 rows x 64 k-elems) of K-tile kt.
// Physical LDS is linear; global source is inverse-swizzled so that reads
// with byte^((row&7)<<4) see the logical layout (rule #21, both-sides).
__device__ __forceinline__ void stage_mat(const char* nsb, char* dst,
                                          int rowbase, int kt, int t, int xs)
{
    #pragma unroll
    for (int h = 0; h < 2; ++h)
        #pragma unroll
        for (int l = 0; l < 2; ++l) {
            const int grow = rowbase + h * 128 + l * 64 + (t >> 3);
            glds16(nsb + (size_t)grow * (DIM * 2) + kt * (BK * 2) + xs,
                   dst + h * 16384 + l * 8192 + t * 16);
        }
}

#define BAR() do { asm volatile("" ::: "memory");                              \
    __builtin_amdgcn_s_barrier(); asm volatile("" ::: "memory"); } while (0)
#define LGKM0() asm volatile("s_waitcnt lgkmcnt(0)" ::: "memory")

__global__ __launch_bounds__(512, 2) void gram_rowsum_kernel(
    const bf16* __restrict__ ns, float* __restrict__ rowsum)
{
    extern __shared__ char smem[];

    // tile decode: raw < NOFF -> strictly-upper (XCD-chunked swizzle, 496=8*62)
    //              raw >= NOFF -> diagonal tiles, dispatched last (LPT)
    const int raw = blockIdx.x;
    int bi, bj, diag;
    if (raw < NOFF) {
        const int idx = (raw & 7) * (NOFF / 8) + (raw >> 3);
        int j = (int)((1.0f + sqrtf(8.0f * (float)idx + 1.0f)) * 0.5f);
        while (j * (j - 1) / 2 > idx) --j;
        while ((j + 1) * j / 2 <= idx) ++j;
        bj = j; bi = idx - j * (j - 1) / 2; diag = 0;
    } else {
        bi = bj = raw - NOFF; diag = 1;
    }

    const int t    = threadIdx.x;
    const int lane = t & 63;
    const int l15  = lane & 15;
    const int wid  = t >> 6;
    const int wr   = wid >> 2;        // 0..1  (128-row half)
    const int wc   = wid & 3;         // 0..3  (64-col quarter)
    // diagonal tile: waves owning the strictly-lower quadrant do no math
    const bool act = !(diag && wr == 1 && wc < 2);

    // staging source pre-swizzle (per-thread constant)
    const int xs  = ((t & 7) * 16) ^ (((t >> 3) & 7) << 4);
    // fragment-read swizzled k-offsets (per-thread constants)
    const int c4  = (lane >> 4) * 16;
    const int sT  = (l15 & 7) << 4;
    const int xo0 = c4 ^ sT;           // k-slice 0
    const int xo1 = (64 + c4) ^ sT;    // k-slice 1

    const char* nsb = (const char*)ns;

    f32x4 acc[8][4];
    #pragma unroll
    for (int m = 0; m < 8; ++m)
        #pragma unroll
        for (int n = 0; n < 4; ++n)
            acc[m][n] = (f32x4)0.f;

    // prologue: stage K-tile 0 into buffer 0 (diag aliases B -> A panel)
    stage_mat(nsb, smem, bi * 256, 0, t, xs);
    if (!diag) stage_mat(nsb, smem + 32768, bj * 256, 0, t, xs);
    asm volatile("s_waitcnt vmcnt(0)" ::: "memory");
    BAR();

    const int aoffR = wr * 128 + l15;
    const int boffR = wc * 64 + l15;

    #pragma unroll
    for (int kt = 0; kt < NKT; ++kt) {
        const char* bufr = smem + (size_t)(kt & 1) * LDS_BUF;
        char*       bufw = smem + (size_t)((kt + 1) & 1) * LDS_BUF;
        const char* A = bufr;
        const char* B = bufr + (diag ? 0 : 32768);
        short8 af[4], bf[4];

        // -------- phase 1: m0-3 x n0-3 x k0 ; stage next A panel ----------
        if (act) {
            #pragma unroll
            for (int m = 0; m < 4; ++m)
                af[m] = *(const short8*)(A + (size_t)(aoffR + m * 16) * 128 + xo0);
            #pragma unroll
            for (int n = 0; n < 4; ++n)
                bf[n] = *(const short8*)(B + (size_t)(boffR + n * 16) * 128 + xo0);
        }
        if (kt < NKT - 1)
            stage_mat(nsb, bufw, bi * 256, kt + 1, t, xs);
        BAR();
        LGKM0();
        __builtin_amdgcn_s_setprio(1);
        if (act) {
            #pragma unroll
            for (int m = 0; m < 4; ++m)
                #pragma unroll
                for (int n = 0; n < 4; ++n)
                    acc[m][n] = __builtin_amdgcn_mfma_f32_16x16x32_bf16(
                        af[m], bf[n], acc[m][n], 0, 0, 0);
        }
        __builtin_amdgcn_s_setprio(0);
        BAR();

        // -------- phase 2: m4-7 x n0-3 x k0 ; stage next B panel ----------
        if (act) {
            #pragma unroll
            for (int m = 0; m < 4; ++m)
                af[m] = *(const short8*)(A + (size_t)(aoffR + (m + 4) * 16) * 128 + xo0);
        }
        if (kt < NKT - 1 && !diag)
            stage_mat(nsb, bufw + 32768, bj * 256, kt + 1, t, xs);
        BAR();
        LGKM0();
        __builtin_amdgcn_s_setprio(1);
        if (act) {
            #pragma unroll
            for (int m = 0; m < 4; ++m)
                #pragma unroll
                for (int n = 0; n < 4; ++n)
                    acc[m + 4][n] = __builtin_amdgcn_mfma_f32_16x16x32_bf16(
                        af[m], bf[n], acc[m + 4][n], 0, 0, 0);
        }
        __builtin_amdgcn_s_setprio(0);
        BAR();

        // -------- phase 3: m0-3 x n0-3 x k1 -------------------------------
        if (act) {
            #pragma unroll
            for (int m = 0; m < 4; ++m)
                af[m] = *(const short8*)(A + (size_t)(aoffR + m * 16) * 128 + xo1);
            #pragma unroll
            for (int n = 0; n < 4; ++n)
                bf[n] = *(const short8*)(B + (size_t)(boffR + n * 16) * 128 + xo1);
        }
        BAR();
        LGKM0();
        __builtin_amdgcn_s_setprio(1);
        if (act) {
            #pragma unroll
            for (int m = 0; m < 4; ++m)
                #pragma unroll
                for (int n = 0; n < 4; ++n)
                    acc[m][n] = __builtin_amdgcn_mfma_f32_16x16x32_bf16(
                        af[m], bf[n], acc[m][n], 0, 0, 0);
        }
        __builtin_amdgcn_s_setprio(0);
        BAR();

        // -------- phase 4: m4-7 x n0-3 x k1 ; drain stale stages ----------
        if (act) {
            #pragma unroll
            for (int m = 0; m < 4; ++m)
                af[m] = *(const short8*)(A + (size_t)(aoffR + (m + 4) * 16) * 128 + xo1);
        }
        BAR();
        LGKM0();
        __builtin_amdgcn_s_setprio(1);
        if (act) {
            #pragma unroll
            for (int m = 0; m < 4; ++m)
                #pragma unroll
                for (int n = 0; n < 4; ++n)
                    acc[m + 4][n] = __builtin_amdgcn_mfma_f32_16x16x32_bf16(
                        af[m], bf[n], acc[m + 4][n], 0, 0, 0);
        }
        __builtin_amdgcn_s_setprio(0);
        // loads being waited were issued 2-3 phases ago -> normally complete
        if (kt < NKT - 1)
            asm volatile("s_waitcnt vmcnt(0)" ::: "memory");
        BAR();
    }

    // ---- epilogue: E = exp(2S); rowsums; colsums (symmetry) --------------
    if (act) {
        #pragma unroll
        for (int m = 0; m < 8; ++m)
            #pragma unroll
            for (int n = 0; n < 4; ++n)
                #pragma unroll
                for (int r = 0; r < 4; ++r)
                    acc[m][n][r] = __expf(2.0f * acc[m][n][r]);

        // C/D layout: row = m*16 + (lane>>4)*4 + reg ; col = n*16 + (lane&15)
        #pragma unroll
        for (int m = 0; m < 8; ++m) {
            #pragma unroll
            for (int r = 0; r < 4; ++r) {
                float p = acc[m][0][r] + acc[m][1][r] + acc[m][2][r] + acc[m][3][r];
                p += __shfl_xor(p, 1);
                p += __shfl_xor(p, 2);
                p += __shfl_xor(p, 4);
                p += __shfl_xor(p, 8);
                if (l15 == 0) {
                    const int row = bi * 256 + wr * 128 + m * 16 + (lane >> 4) * 4 + r;
                    atomicAdd(&rowsum[row], p);
                }
            }
        }
        // off-diag: all waves add colsums (symmetry for the bj panel rows).
        // diag: only the strictly-upper quadrant waves (wr==0, wc>=2) add
        // colsums — these supply the rowsums of the skipped lower quadrant.
        const bool do_col = (!diag) || (wr == 0 && wc >= 2);
        if (do_col) {
            #pragma unroll
            for (int n = 0; n < 4; ++n) {
                float q = 0.f;
                #pragma unroll
                for (int m = 0; m < 8; ++m)
                    #pragma unroll
                    for (int r = 0; r < 4; ++r)
                        q += acc[m][n][r];
                q += __shfl_xor(q, 16);
                q += __shfl_xor(q, 32);
                if (lane < 16) {
                    const int col = bj * 256 + wc * 64 + n * 16 + lane;
                    atomicAdd(&rowsum[col], q);
                }
            }
        }
    }
}

// ---------------------------------------------------------------------------
// Kernel 3: finalize -> loss (unchanged)
// ---------------------------------------------------------------------------
__global__ __launch_bounds__(256) void finalize_kernel(
    const float* __restrict__ rowsum, const float* __restrict__ pospart,
    float* __restrict__ out)
{
    const int t = threadIdx.x;
    float s = 0.f;
    for (int r = t; r < M2; r += 256)
        s += logf(rowsum[r] - SELF_EXP);
    float pp = 0.f;
    for (int r = t; r < NROW; r += 256)
        pp += pospart[r];
    #pragma unroll
    for (int o = 1; o < 64; o <<= 1) {
        s  += __shfl_xor(s, o);
        pp += __shfl_xor(pp, o);
    }
    __shared__ float rd[8];
    if ((t & 63) == 0) { rd[t >> 6] = s; rd[4 + (t >> 6)] = pp; }
    __syncthreads();
    if (t == 0) {
        const float term2 = rd[0] + rd[1] + rd[2] + rd[3];
        const float term1 = 4.0f * (rd[4] + rd[5] + rd[6] + rd[7]);
        out[0] = (term2 - term1) / (float)M2;
    }
}

// ---------------------------------------------------------------------------
extern "C" void kernel_launch(void* const* d_in, const int* in_sizes, int n_in,
                              void* d_out, int out_size, void* d_ws, size_t ws_size,
                              hipStream_t stream)
{
    const float* x = (const float*)d_in[0];
    const float* y = (const float*)d_in[1];
    float* out = (float*)d_out;

    char* ws = (char*)d_ws;
    bf16*  ns      = (bf16*)ws;                               // 8 MiB
    float* rowsum  = (float*)(ws + (size_t)8 * 1024 * 1024);  // 32 KiB
    float* pospart = rowsum + M2;                             // 16 KiB

    // allow >64 KiB dynamic LDS (no-op/ignored where not needed)
    static bool attr_set = false;
    if (!attr_set) {
        (void)hipFuncSetAttribute((const void*)gram_rowsum_kernel,
                                  hipFuncAttributeMaxDynamicSharedMemorySize,
                                  LDS_TOTAL);
        attr_set = true;
    }

    norm_pos_kernel<<<NROW, 256, 0, stream>>>(x, y, ns, pospart, rowsum);

    gram_rowsum_kernel<<<NBLK, 512, LDS_TOTAL, stream>>>(ns, rowsum);

    finalize_kernel<<<1, 256, 0, stream>>>(rowsum, pospart, out);
}

// Round 2
// 87.920 us; speedup vs baseline: 1.0642x; 1.0642x over previous
//
#include <hip/hip_runtime.h>
#include <hip/hip_bf16.h>
#include <math.h>

#define NROW 4096
#define DIM  512
#define M2   8192                     // 2N rows
#define SELF_EXP 7.3890560989306495f  // exp(1/T) = exp(2)
#define TGRID 32                      // M2 / 256 tile grid
#define NOFF  (TGRID * (TGRID - 1) / 2)   // 496 strictly-upper tiles (8*62)
#define NBLK  (NOFF + TGRID)              // 528 total (32 diagonal last)
#define BK    32                      // K-step (elements)
#define NKT   (DIM / BK)              // 16 K-steps
#define LDS_TOTAL 131072              // ring of 4 x (A 16K + B 16K)

typedef __hip_bfloat16 bf16;
typedef __attribute__((ext_vector_type(8))) short short8;   // 8 bf16 (4 VGPRs)
typedef __attribute__((ext_vector_type(4))) float f32x4;

// ---------------------------------------------------------------------------
// Kernel 1: fused row-normalize (x,y -> bf16 ns[8192][512]) + positive-pair
// cosine partial + rowsum zeroing + out zeroing.
// ---------------------------------------------------------------------------
__global__ __launch_bounds__(256) void norm_pos_kernel(
    const float* __restrict__ x, const float* __restrict__ y,
    bf16* __restrict__ ns, float* __restrict__ pospart,
    float* __restrict__ rowsum, float* __restrict__ out)
{
    const int i = blockIdx.x;
    const int t = threadIdx.x;
    const float2 a = ((const float2*)(x + (size_t)i * DIM))[t];
    const float2 b = ((const float2*)(y + (size_t)i * DIM))[t];
    float sx = a.x * a.x + a.y * a.y;
    float sy = b.x * b.x + b.y * b.y;
    float dt = a.x * b.x + a.y * b.y;
    #pragma unroll
    for (int o = 1; o < 64; o <<= 1) {
        sx += __shfl_xor(sx, o);
        sy += __shfl_xor(sy, o);
        dt += __shfl_xor(dt, o);
    }
    __shared__ float rd[12];
    const int wid = t >> 6, lane = t & 63;
    if (lane == 0) { rd[wid] = sx; rd[4 + wid] = sy; rd[8 + wid] = dt; }
    __syncthreads();
    const float SX = rd[0] + rd[1] + rd[2] + rd[3];
    const float SY = rd[4] + rd[5] + rd[6] + rd[7];
    const float D  = rd[8] + rd[9] + rd[10] + rd[11];
    const float rnx = rsqrtf(SX), rny = rsqrtf(SY);

    bf16 a0 = __float2bfloat16(a.x * rnx), a1 = __float2bfloat16(a.y * rnx);
    bf16 b0 = __float2bfloat16(b.x * rny), b1 = __float2bfloat16(b.y * rny);
    ushort2 sa, sb;
    sa.x = *(unsigned short*)&a0; sa.y = *(unsigned short*)&a1;
    sb.x = *(unsigned short*)&b0; sb.y = *(unsigned short*)&b1;
    ((ushort2*)(void*)(ns + (size_t)i * DIM))[t] = sa;
    ((ushort2*)(void*)(ns + (size_t)(i + NROW) * DIM))[t] = sb;

    if (t == 0) pospart[i] = D * rnx * rny;
    if (t < 2)  rowsum[2 * i + t] = 0.f;
    if (i == 0 && t == 0) out[0] = 0.f;
}

// ---------------------------------------------------------------------------
// Kernel 2: symmetric Gram, 256x256 tiles, 8 waves, BK=32, RING-4 LDS
// (4 x 32 KiB) with counted vmcnt: stage K-step kt+3 during kt, wait
// vmcnt(12) (3 steps in flight) -> never drains to 0 in steady state
// (T4, m218). T2 swizzle (row&3)<<4 both-sides (2-way alias = free),
// T5 setprio around the 32-MFMA cluster, 2 barriers per K-step.
// Upper-triangle tiles first (XCD-chunked), 32 diagonal tiles last.
// ---------------------------------------------------------------------------
__device__ __forceinline__ void glds16(const char* g, char* l)
{
    __builtin_amdgcn_global_load_lds(
        (const __attribute__((address_space(1))) void*)g,
        (__attribute__((address_space(3))) void*)l, 16, 0, 0);
}

// Stage one 16 KiB panel (256 rows x 32 k-elems) of K-step kt.
// Linear LDS dest; global source inverse-swizzled (rule #21 both-sides):
// logical slot s of row r lives at physical s ^ (r&3).
__device__ __forceinline__ void stage_panel(const char* nsb, char* dst,
                                            int rowbase, int kt, int t)
{
    #pragma unroll
    for (int l = 0; l < 2; ++l) {
        const int o   = (l * 512 + t) * 16;             // 0..16383
        const int row = o >> 6;                         // 64 B per LDS row
        const int src = (((o >> 4) & 3) ^ (row & 3)) << 4;
        glds16(nsb + (size_t)(rowbase + row) * (DIM * 2) + kt * (BK * 2) + src,
               dst + o);
    }
}

#define BAR() do { asm volatile("" ::: "memory");                              \
    __builtin_amdgcn_s_barrier(); asm volatile("" ::: "memory"); } while (0)
#define VMCNT(n) asm volatile("s_waitcnt vmcnt(" #n ")" ::: "memory")

template<int DIAG>
__device__ __forceinline__ void gram_loop(
    const char* nsb, char* smem, int bi, int bj, int t, bool act,
    f32x4 (&acc)[8][4])
{
    const int lane = t & 63, l15 = lane & 15;
    const int wid = t >> 6, wr = wid >> 2, wc = wid & 3;
    const int xo = ((lane >> 4) * 16) ^ ((l15 & 3) << 4);   // swizzled frag off
    const int aR = wr * 128 + l15;
    const int bR = wc * 64 + l15;
    const int STEP = DIAG ? 16384 : 32768;                  // diag: B aliases A

    // prologue: stage K-steps 0..2
    #pragma unroll
    for (int s = 0; s < 3; ++s) {
        stage_panel(nsb, smem + s * STEP, bi * 256, s, t);
        if (!DIAG) stage_panel(nsb, smem + s * STEP + 16384, bj * 256, s, t);
    }

    #pragma unroll
    for (int kt = 0; kt < NKT; ++kt) {
        // all waves finished reading buf[(kt-1)&3] -> safe to overwrite
        BAR();
        if (kt + 3 < NKT) {
            char* bw = smem + ((kt + 3) & 3) * STEP;
            stage_panel(nsb, bw, bi * 256, kt + 3, t);
            if (!DIAG) stage_panel(nsb, bw + 16384, bj * 256, kt + 3, t);
        }
        // counted wait: own stage(kt) loads complete, deeper stages in flight
        if (kt < NKT - 3)       { if (DIAG) VMCNT(6); else VMCNT(12); }
        else if (kt == NKT - 3) { if (DIAG) VMCNT(4); else VMCNT(8); }
        else if (kt == NKT - 2) { if (DIAG) VMCNT(2); else VMCNT(4); }
        else                    VMCNT(0);
        BAR();   // all waves' stage(kt) complete -> buf[kt&3] valid

        const char* A = smem + (kt & 3) * STEP;
        const char* B = DIAG ? A : (A + 16384);
        if (act) {
            short8 af[8], bf[4];
            #pragma unroll
            for (int m = 0; m < 8; ++m)
                af[m] = *(const short8*)(A + (size_t)(aR + m * 16) * 64 + xo);
            #pragma unroll
            for (int n = 0; n < 4; ++n)
                bf[n] = *(const short8*)(B + (size_t)(bR + n * 16) * 64 + xo);
            __builtin_amdgcn_s_setprio(1);
            #pragma unroll
            for (int m = 0; m < 8; ++m)
                #pragma unroll
                for (int n = 0; n < 4; ++n)
                    acc[m][n] = __builtin_amdgcn_mfma_f32_16x16x32_bf16(
                        af[m], bf[n], acc[m][n], 0, 0, 0);
            __builtin_amdgcn_s_setprio(0);
        }
    }
}

__global__ __launch_bounds__(512, 2) void gram_rowsum_kernel(
    const bf16* __restrict__ ns, float* __restrict__ rowsum)
{
    extern __shared__ char smem[];

    const int raw = blockIdx.x;
    int bi, bj, diag;
    if (raw < NOFF) {
        const int idx = (raw & 7) * (NOFF / 8) + (raw >> 3);
        int j = (int)((1.0f + sqrtf(8.0f * (float)idx + 1.0f)) * 0.5f);
        while (j * (j - 1) / 2 > idx) --j;
        while ((j + 1) * j / 2 <= idx) ++j;
        bj = j; bi = idx - j * (j - 1) / 2; diag = 0;
    } else {
        bi = bj = raw - NOFF; diag = 1;
    }

    const int t    = threadIdx.x;
    const int lane = t & 63;
    const int l15  = lane & 15;
    const int wid  = t >> 6;
    const int wr   = wid >> 2;        // 0..1  (128-row half)
    const int wc   = wid & 3;         // 0..3  (64-col quarter)
    const bool act = !(diag && wr == 1 && wc < 2);

    f32x4 acc[8][4];
    #pragma unroll
    for (int m = 0; m < 8; ++m)
        #pragma unroll
        for (int n = 0; n < 4; ++n)
            acc[m][n] = (f32x4)0.f;

    const char* nsb = (const char*)ns;
    if (diag) gram_loop<1>(nsb, smem, bi, bj, t, act, acc);
    else      gram_loop<0>(nsb, smem, bi, bj, t, act, acc);

    // ---- epilogue: E = exp(2S); rowsums; colsums (symmetry) --------------
    if (act) {
        #pragma unroll
        for (int m = 0; m < 8; ++m)
            #pragma unroll
            for (int n = 0; n < 4; ++n)
                #pragma unroll
                for (int r = 0; r < 4; ++r)
                    acc[m][n][r] = __expf(2.0f * acc[m][n][r]);

        // C/D layout: row = m*16 + (lane>>4)*4 + reg ; col = n*16 + (lane&15)
        #pragma unroll
        for (int m = 0; m < 8; ++m) {
            #pragma unroll
            for (int r = 0; r < 4; ++r) {
                float p = acc[m][0][r] + acc[m][1][r] + acc[m][2][r] + acc[m][3][r];
                p += __shfl_xor(p, 1);
                p += __shfl_xor(p, 2);
                p += __shfl_xor(p, 4);
                p += __shfl_xor(p, 8);
                if (l15 == 0) {
                    const int row = bi * 256 + wr * 128 + m * 16 + (lane >> 4) * 4 + r;
                    atomicAdd(&rowsum[row], p);
                }
            }
        }
        const bool do_col = (!diag) || (wr == 0 && wc >= 2);
        if (do_col) {
            #pragma unroll
            for (int n = 0; n < 4; ++n) {
                float q = 0.f;
                #pragma unroll
                for (int m = 0; m < 8; ++m)
                    #pragma unroll
                    for (int r = 0; r < 4; ++r)
                        q += acc[m][n][r];
                q += __shfl_xor(q, 16);
                q += __shfl_xor(q, 32);
                if (lane < 16) {
                    const int col = bj * 256 + wc * 64 + n * 16 + lane;
                    atomicAdd(&rowsum[col], q);
                }
            }
        }
    }
}

// ---------------------------------------------------------------------------
// Kernel 3: finalize -> loss, parallel (32 blocks, atomicAdd into out)
// ---------------------------------------------------------------------------
__global__ __launch_bounds__(256) void finalize_kernel(
    const float* __restrict__ rowsum, const float* __restrict__ pospart,
    float* __restrict__ out)
{
    const int b = blockIdx.x, t = threadIdx.x;
    float s  = logf(rowsum[b * 256 + t] - SELF_EXP);
    float pp = (t < 128) ? pospart[b * 128 + t] : 0.f;
    #pragma unroll
    for (int o = 1; o < 64; o <<= 1) {
        s  += __shfl_xor(s, o);
        pp += __shfl_xor(pp, o);
    }
    __shared__ float rd[8];
    if ((t & 63) == 0) { rd[t >> 6] = s; rd[4 + (t >> 6)] = pp; }
    __syncthreads();
    if (t == 0) {
        const float ts = rd[0] + rd[1] + rd[2] + rd[3];
        const float tp = rd[4] + rd[5] + rd[6] + rd[7];
        atomicAdd(out, (ts - 4.0f * tp) / (float)M2);
    }
}

// ---------------------------------------------------------------------------
extern "C" void kernel_launch(void* const* d_in, const int* in_sizes, int n_in,
                              void* d_out, int out_size, void* d_ws, size_t ws_size,
                              hipStream_t stream)
{
    const float* x = (const float*)d_in[0];
    const float* y = (const float*)d_in[1];
    float* out = (float*)d_out;

    char* ws = (char*)d_ws;
    bf16*  ns      = (bf16*)ws;                               // 8 MiB
    float* rowsum  = (float*)(ws + (size_t)8 * 1024 * 1024);  // 32 KiB
    float* pospart = rowsum + M2;                             // 16 KiB

    static bool attr_set = false;
    if (!attr_set) {
        (void)hipFuncSetAttribute((const void*)gram_rowsum_kernel,
                                  hipFuncAttributeMaxDynamicSharedMemorySize,
                                  LDS_TOTAL);
        attr_set = true;
    }

    norm_pos_kernel<<<NROW, 256, 0, stream>>>(x, y, ns, pospart, rowsum, out);

    gram_rowsum_kernel<<<NBLK, 512, LDS_TOTAL, stream>>>(ns, rowsum);

    finalize_kernel<<<32, 256, 0, stream>>>(rowsum, pospart, out);
}